// Round 7
// baseline (167.240 us; speedup 1.0000x reference)
//
#include <hip/hip_runtime.h>
#include <stdint.h>

// Problem constants (B=2,S=1024,D=1024,F=4096,E=8)
#define T_TOK 2048
#define D_DIM 1024
#define F_DIM 4096
#define E_NUM 8
#define RPMAX 3072   // max padded rows: sum of per-expert ceil(cnt,128)
#define BK 64

typedef __attribute__((ext_vector_type(8))) short bfx8;   // 8 bf16 (4 VGPR)
typedef __attribute__((ext_vector_type(4))) float fx4;    // MFMA accum / staging

__device__ __forceinline__ unsigned short f2bf(float f) {
  union { float f; uint32_t u; } v; v.f = f;
  uint32_t u = v.u;
  u += 0x7FFFu + ((u >> 16) & 1u);   // round-to-nearest-even
  return (unsigned short)(u >> 16);
}

__device__ __forceinline__ void load_lds16(const unsigned short* g, unsigned short* l) {
  __builtin_amdgcn_global_load_lds(
      (const __attribute__((address_space(1))) void*)g,
      (__attribute__((address_space(3))) void*)l, 16, 0, 0);
}

__device__ __forceinline__ uint32_t cvtpk_bf16(float lo, float hi) {
  uint32_t d;
  asm("v_cvt_pk_bf16_f32 %0, %1, %2" : "=v"(d) : "v"(lo), "v"(hi));
  return d;
}

template <int N>
__device__ __forceinline__ void vm_wait_lgkm() {
  if constexpr (N == 0) asm volatile("s_waitcnt vmcnt(0) lgkmcnt(0)" ::: "memory");
  else if constexpr (N == 6) asm volatile("s_waitcnt vmcnt(6) lgkmcnt(0)" ::: "memory");
  else if constexpr (N == 8) asm volatile("s_waitcnt vmcnt(8) lgkmcnt(0)" ::: "memory");
}

// ---------------- router: logits, softmax, argmax; NO global atomics ----------------
__global__ __launch_bounds__(256) void router_kernel(
    const float* __restrict__ x, const float* __restrict__ sw,
    const float* __restrict__ sb, float* __restrict__ pmax_out,
    int* __restrict__ routes, float* __restrict__ probs,
    unsigned short* __restrict__ xbf) {
  const int wave = threadIdx.x >> 6, lane = threadIdx.x & 63;
  const int t = blockIdx.x * 4 + wave;
  const float* xr = x + (size_t)t * D_DIM;
  float acc[8];
#pragma unroll
  for (int e = 0; e < 8; ++e) acc[e] = 0.f;
#pragma unroll
  for (int i = 0; i < 4; ++i) {
    const int d = i * 256 + lane * 4;
    float4 xv = *(const float4*)(xr + d);
    ushort4 h;
    h.x = f2bf(xv.x); h.y = f2bf(xv.y); h.z = f2bf(xv.z); h.w = f2bf(xv.w);
    *(ushort4*)(xbf + (size_t)t * D_DIM + d) = h;
    const float xs[4] = {xv.x, xv.y, xv.z, xv.w};
#pragma unroll
    for (int j = 0; j < 4; ++j) {
      const float4* swp = (const float4*)(sw + (size_t)(d + j) * 8);
      float4 w0 = swp[0], w1 = swp[1];
      acc[0] += xs[j] * w0.x; acc[1] += xs[j] * w0.y;
      acc[2] += xs[j] * w0.z; acc[3] += xs[j] * w0.w;
      acc[4] += xs[j] * w1.x; acc[5] += xs[j] * w1.y;
      acc[6] += xs[j] * w1.z; acc[7] += xs[j] * w1.w;
    }
  }
#pragma unroll
  for (int e = 0; e < 8; ++e) {
    float v = acc[e];
    for (int o = 32; o > 0; o >>= 1) v += __shfl_down(v, o, 64);
    acc[e] = v;
  }
  if (lane == 0) {
#pragma unroll
    for (int e = 0; e < 8; ++e) acc[e] += sb[e];
    int am = 0; float mx = acc[0];
#pragma unroll
    for (int e = 1; e < 8; ++e) if (acc[e] > mx) { mx = acc[e]; am = e; }  // first-max wins
    float p[8]; float s = 0.f;
#pragma unroll
    for (int e = 0; e < 8; ++e) { p[e] = expf(acc[e] - mx); s += p[e]; }
    float inv = 1.0f / s;
    pmax_out[t] = inv;
    routes[t] = am;
#pragma unroll
    for (int e = 0; e < 8; ++e) probs[(size_t)t * 8 + e] = p[e] * inv;
  }
}

// ---------------- plan: counts/psums reduce, offsets, cursor zero, perm init ----------
__global__ __launch_bounds__(256) void plan_kernel(
    const int* __restrict__ routes, const float* __restrict__ probs,
    int* __restrict__ off, int* __restrict__ cursor,
    int* __restrict__ perm_out, int* __restrict__ perm_src,
    float* __restrict__ out_counts, float* __restrict__ out_psums,
    float* __restrict__ out_zero) {
  __shared__ int cnt[8];
  __shared__ float red[256][8];
  const int tid = threadIdx.x;
  if (tid < 8) { cnt[tid] = 0; cursor[tid] = 0; }
  for (int i = tid; i < RPMAX; i += 256) { perm_out[i] = -1; perm_src[i] = 0; }
  __syncthreads();
  float loc[8];
#pragma unroll
  for (int e = 0; e < 8; ++e) loc[e] = 0.f;
  for (int t = tid; t < T_TOK; t += 256) {
    atomicAdd(&cnt[routes[t]], 1);
    const float4* p = (const float4*)(probs + (size_t)t * 8);
    float4 a = p[0], b = p[1];
    loc[0] += a.x; loc[1] += a.y; loc[2] += a.z; loc[3] += a.w;
    loc[4] += b.x; loc[5] += b.y; loc[6] += b.z; loc[7] += b.w;
  }
#pragma unroll
  for (int e = 0; e < 8; ++e) red[tid][e] = loc[e];
  __syncthreads();
  for (int s = 128; s >= 1; s >>= 1) {
    if (tid < s) {
#pragma unroll
      for (int e = 0; e < 8; ++e) red[tid][e] += red[tid + s][e];
    }
    __syncthreads();
  }
  if (tid == 0) {
    int o = 0;
    for (int e = 0; e < 8; ++e) { off[e] = o; o += ((cnt[e] + 127) >> 7) << 7; }
    off[8] = o;
    *out_zero = 0.0f;
  }
  if (tid < 8) {
    out_counts[tid] = (float)cnt[tid];
    out_psums[tid] = red[0][tid];
  }
}

// ---------------- scatter: token -> gathered slot ----------------
__global__ __launch_bounds__(256) void scatter_kernel(
    const int* __restrict__ routes, const int* __restrict__ off,
    int* __restrict__ cursor, int* __restrict__ perm_out,
    int* __restrict__ perm_src) {
  int t = blockIdx.x * 256 + threadIdx.x;
  if (t >= T_TOK) return;
  int e = routes[t];
  int pos = atomicAdd(&cursor[e], 1);
  perm_out[off[e] + pos] = t;
  perm_src[off[e] + pos] = t;
}

// ---------------- fused grouped GEMM, deep pipeline, 64x64 tile ----------------
// 4 waves (2m x 2n), each wave 32x32 out (2x2 frags). LDS 40KB -> 4 blocks/CU.
// A bf16 via global_load_lds staged TWO K-steps ahead (3 rotating bufs, key row&7).
// B: fp32 W -> float4 (depth-2 reg prefetch) -> cvt_pk bf16 -> 4x4 reg transpose ->
// ds_write_b64, key ((nl>>2)+2*(nl&3))&7. One barrier/K-step; vmcnt floor 6.
template <int K_, int N_, bool FIRST, bool NCHUNK>
__global__ __launch_bounds__(256, 4) void gemm_fused(
    const unsigned short* __restrict__ A,    // FIRST: xbf [T][K_]; else H [RP][K_]
    const float* __restrict__ W,             // [E][K_][N_] fp32
    const float* __restrict__ Bias,          // [E][N_]
    const int* __restrict__ off,
    const int* __restrict__ perm_src, const int* __restrict__ perm_out,
    const float* __restrict__ pmax,
    unsigned short* __restrict__ Hout, float* __restrict__ Out) {
  constexpr int NT = K_ / BK;                // 16 or 64 (even, >=4)
  __shared__ __align__(16) unsigned short As[3][64 * 64];
  __shared__ __align__(16) unsigned short Bs[2][64 * 64];
  const int tid = threadIdx.x;
  // XCD-chunked bijective swizzle (grid size multiple of 8)
  const int nbx = gridDim.x, nby = gridDim.y;
  const int lin = blockIdx.y * nbx + blockIdx.x;
  const int chunkg = (nbx * nby) >> 3;
  const int newlin = (lin & 7) * chunkg + (lin >> 3);
  const int bx = NCHUNK ? (newlin / nby) : (newlin % nbx);
  const int by = NCHUNK ? (newlin % nby) : (newlin / nbx);
  const int rowbase = by * 64;               // 64 | 128-aligned segments -> single expert
  if (rowbase >= off[8]) return;
  int e = 0;
#pragma unroll
  for (int i = 1; i <= 7; ++i) if (rowbase >= off[i]) e = i;
  const int n0 = bx * 64;
  const int wave = tid >> 6, lane = tid & 63;
  const int wm = wave >> 1, wn = wave & 1;
  const float* Wn0 = W + (size_t)e * K_ * N_ + n0;

  // A: per-lane pre-swizzled global sources; LDS linear, src chunk XOR'd (key row&7)
  const unsigned short* aSrc[2];
#pragma unroll
  for (int c = 0; c < 2; ++c) {
    int ca = (wave * 2 + c) * 64 + lane;      // 16B-chunk id, 0..511
    int row = ca >> 3, slot = ca & 7;
    int sc = slot ^ (row & 7);
    size_t arow = FIRST ? (size_t)perm_src[rowbase + row] : (size_t)(rowbase + row);
    aSrc[c] = A + arow * K_ + sc * 8;
  }

  const int nq = lane & 15;                  // n-quad 0..15
  const int qg = lane >> 4;                  // k-quad group 0..3
  fx4 bregE[4], bregO[4];                    // depth-2 B prefetch register sets

  auto A_STAGE = [&](int kt, unsigned short* Asb) {
#pragma unroll
    for (int c = 0; c < 2; ++c)
      load_lds16(aSrc[c] + kt, Asb + (wave * 2 + c) * 512);
  };
  auto B_LOAD = [&](int kt, fx4* br) {
#pragma unroll
    for (int j = 0; j < 4; ++j)
      br[j] = *(const fx4*)(Wn0 + (size_t)(kt + wave * 16 + qg * 4 + j) * N_ + nq * 4);
  };
  auto B_STORE = [&](fx4* br, unsigned short* Bsb) {
    const int c16 = wave * 2 + (qg >> 1);
    const int h4 = (qg & 1) * 4;             // 8B half (u16 units)
#pragma unroll
    for (int i = 0; i < 4; ++i) {
      const int nl = nq * 4 + i;
      const int key = ((nl >> 2) + 2 * (nl & 3)) & 7;
      uint32_t d0 = cvtpk_bf16(br[0][i], br[1][i]);
      uint32_t d1 = cvtpk_bf16(br[2][i], br[3][i]);
      *(uint2*)(Bsb + nl * 64 + (c16 ^ key) * 8 + h4) = make_uint2(d0, d1);
    }
  };

  fx4 acc[2][2];
#pragma unroll
  for (int a = 0; a < 2; ++a)
#pragma unroll
    for (int b = 0; b < 2; ++b) acc[a][b] = (fx4){0.f, 0.f, 0.f, 0.f};

  auto COMPUTE = [&](const unsigned short* Asb, const unsigned short* Bsb) {
    __builtin_amdgcn_s_setprio(1);
#pragma unroll
    for (int kk = 0; kk < 2; ++kk) {
      bfx8 af[2], bf[2];
#pragma unroll
      for (int fm = 0; fm < 2; ++fm) {
        int r = wm * 32 + fm * 16 + (lane & 15);
        int c = (kk * 4 + (lane >> 4)) ^ (r & 7);
        af[fm] = *(const bfx8*)(Asb + r * 64 + c * 8);
      }
#pragma unroll
      for (int fn = 0; fn < 2; ++fn) {
        int nn = wn * 32 + fn * 16 + (lane & 15);
        int key = ((nn >> 2) + 2 * (nn & 3)) & 7;
        int c = (kk * 4 + (lane >> 4)) ^ key;
        bf[fn] = *(const bfx8*)(Bsb + nn * 64 + c * 8);
      }
#pragma unroll
      for (int fm = 0; fm < 2; ++fm)
#pragma unroll
        for (int fn = 0; fn < 2; ++fn)
          acc[fm][fn] = __builtin_amdgcn_mfma_f32_16x16x32_bf16(
              af[fm], bf[fn], acc[fm][fn], 0, 0, 0);
    }
    __builtin_amdgcn_s_setprio(0);
  };

  unsigned short *a0 = As[0], *a1 = As[1], *a2 = As[2];

  // ---- prologue: A0,B0,A1,B1 issued in FIFO order; store B0; barrier ----
  A_STAGE(0, a0);
  __builtin_amdgcn_sched_barrier(0);
  B_LOAD(0, bregE);
  __builtin_amdgcn_sched_barrier(0);
  A_STAGE(BK, a1);
  __builtin_amdgcn_sched_barrier(0);
  B_LOAD(BK, bregO);
  B_STORE(bregE, Bs[0]);                     // implicit reg-wait drains A0,B0
  vm_wait_lgkm<6>();                         // A1+B1 stay in flight
  __builtin_amdgcn_s_barrier();

  // ---- main loop: pairs; compute t from a0/Bs[t&1]; stage A(t+2)->a2, B(t+2) ----
  for (int t = 0; t < NT - 2; t += 2) {
    // even iter t
    A_STAGE((t + 2) * BK, a2);
    __builtin_amdgcn_sched_barrier(0);
    B_LOAD((t + 2) * BK, bregE);
    COMPUTE(a0, Bs[0]);
    B_STORE(bregO, Bs[1]);                   // waits B(t+1) -> drains A(t+1)
    vm_wait_lgkm<6>();                       // A(t+2)+B(t+2) remain in flight
    __builtin_amdgcn_s_barrier();
    { unsigned short* tmp = a0; a0 = a1; a1 = a2; a2 = tmp; }
    // odd iter t+1
    if (t + 3 < NT) {
      A_STAGE((t + 3) * BK, a2);
      __builtin_amdgcn_sched_barrier(0);
      B_LOAD((t + 3) * BK, bregO);
    }
    COMPUTE(a0, Bs[1]);
    B_STORE(bregE, Bs[0]);                   // waits B(t+2) -> drains A(t+2)
    vm_wait_lgkm<6>();
    __builtin_amdgcn_s_barrier();
    { unsigned short* tmp = a0; a0 = a1; a1 = a2; a2 = tmp; }
  }
  // tail: iter NT-2 (even), nothing new to issue
  COMPUTE(a0, Bs[0]);
  B_STORE(bregO, Bs[1]);                     // B(NT-1); drains A(NT-1)
  vm_wait_lgkm<0>();
  __builtin_amdgcn_s_barrier();
  { unsigned short* tmp = a0; a0 = a1; a1 = a2; a2 = tmp; }
  COMPUTE(a0, Bs[1]);                        // iter NT-1

  // ---- epilogue ----
  const int colbase = n0 + wn * 32;
  if (FIRST) {
#pragma unroll
    for (int fn = 0; fn < 2; ++fn) {
      int colg = colbase + fn * 16 + (lane & 15);
      float bv = Bias[(size_t)e * N_ + colg];
#pragma unroll
      for (int fm = 0; fm < 2; ++fm) {
        int rg = rowbase + wm * 32 + fm * 16 + ((lane >> 4) << 2);
#pragma unroll
        for (int j = 0; j < 4; ++j) {
          float v = fmaxf(acc[fm][fn][j] + bv, 0.f);
          Hout[(size_t)(rg + j) * N_ + colg] = f2bf(v);
        }
      }
    }
  } else {
#pragma unroll
    for (int fm = 0; fm < 2; ++fm) {
      int rg = rowbase + wm * 32 + fm * 16 + ((lane >> 4) << 2);
#pragma unroll
      for (int j = 0; j < 4; ++j) {
        int tok = perm_out[rg + j];
        if (tok < 0) continue;
        float pm = pmax[tok];
#pragma unroll
        for (int fn = 0; fn < 2; ++fn) {
          int colg = colbase + fn * 16 + (lane & 15);
          Out[(size_t)tok * N_ + colg] = (acc[fm][fn][j] + Bias[(size_t)e * N_ + colg]) * pm;
        }
      }
    }
  }
}

extern "C" void kernel_launch(void* const* d_in, const int* in_sizes, int n_in,
                              void* d_out, int out_size, void* d_ws, size_t ws_size,
                              hipStream_t stream) {
  const float* x  = (const float*)d_in[0];
  const float* sw = (const float*)d_in[1];
  const float* sb = (const float*)d_in[2];
  const float* w1 = (const float*)d_in[3];
  const float* b1 = (const float*)d_in[4];
  const float* w2 = (const float*)d_in[5];
  const float* b2 = (const float*)d_in[6];
  float* out = (float*)d_out;

  char* ws = (char*)d_ws;
  int*   off      = (int*)(ws + 0);          // 9 ints
  int*   cursor   = (int*)(ws + 512);        // 8 ints
  int*   routes   = (int*)(ws + 1024);       // 2048 ints
  int*   perm_out = (int*)(ws + 16384);      // RPMAX ints (pads -1)
  int*   perm_src = (int*)(ws + 32768);      // RPMAX ints (pads 0)
  float* probs    = (float*)(ws + 49152);    // 2048x8 fp32
  unsigned short* xbf = (unsigned short*)(ws + (1u << 20));   // 4 MB
  unsigned short* H   = (unsigned short*)(ws + (8u << 20));   // RPMAX x 4096 bf16 = 24 MB

  // d_out layout: final(2097152) | counts(8) | psums(8) | 0(1) | pmax(2048)
  float* out_final  = out;
  float* out_counts = out + 2097152;
  float* out_psums  = out + 2097160;
  float* out_zero   = out + 2097168;
  float* out_pmax   = out + 2097169;

  router_kernel<<<T_TOK / 4, 256, 0, stream>>>(x, sw, sb, out_pmax, routes, probs, xbf);
  plan_kernel<<<1, 256, 0, stream>>>(routes, probs, off, cursor, perm_out, perm_src,
                                     out_counts, out_psums, out_zero);
  scatter_kernel<<<(T_TOK + 255) / 256, 256, 0, stream>>>(routes, off, cursor,
                                                          perm_out, perm_src);

  // GEMM1: gather(xbf)[RP,1024] x W1 -> H (relu, bf16). n-chunked XCD swizzle.
  gemm_fused<D_DIM, F_DIM, true, true>
      <<<dim3(F_DIM / 64, RPMAX / 64), 256, 0, stream>>>(
          xbf, w1, b1, off, perm_src, perm_out, nullptr, H, nullptr);
  // GEMM2: H[RP,4096] x W2 -> out (bias, *pmax, scatter fp32). m-chunked swizzle.
  gemm_fused<F_DIM, D_DIM, false, false>
      <<<dim3(D_DIM / 64, RPMAX / 64), 256, 0, stream>>>(
          H, w2, b2, off, perm_src, perm_out, out_pmax, nullptr, out_final);
}

// Round 8
// 166.759 us; speedup vs baseline: 1.0029x; 1.0029x over previous
//
#include <hip/hip_runtime.h>
#include <stdint.h>

// Problem constants (B=2,S=1024,D=1024,F=4096,E=8)
#define T_TOK 2048
#define D_DIM 1024
#define F_DIM 4096
#define E_NUM 8
#define RPMAX 3072   // max padded rows: sum of per-expert ceil(cnt,128)
#define BK 64

typedef __attribute__((ext_vector_type(8))) short bfx8;   // 8 bf16 (4 VGPR)
typedef __attribute__((ext_vector_type(4))) float fx4;    // MFMA accum / staging

__device__ __forceinline__ unsigned short f2bf(float f) {
  union { float f; uint32_t u; } v; v.f = f;
  uint32_t u = v.u;
  u += 0x7FFFu + ((u >> 16) & 1u);   // round-to-nearest-even
  return (unsigned short)(u >> 16);
}

__device__ __forceinline__ void load_lds16(const unsigned short* g, unsigned short* l) {
  __builtin_amdgcn_global_load_lds(
      (const __attribute__((address_space(1))) void*)g,
      (__attribute__((address_space(3))) void*)l, 16, 0, 0);
}

__device__ __forceinline__ uint32_t cvtpk_bf16(float lo, float hi) {
  uint32_t d;
  asm("v_cvt_pk_bf16_f32 %0, %1, %2" : "=v"(d) : "v"(lo), "v"(hi));
  return d;
}

template <int N>
__device__ __forceinline__ void vm_wait_lgkm() {
  if constexpr (N == 0) asm volatile("s_waitcnt vmcnt(0) lgkmcnt(0)" ::: "memory");
  else if constexpr (N == 8) asm volatile("s_waitcnt vmcnt(8) lgkmcnt(0)" ::: "memory");
  else if constexpr (N == 12) asm volatile("s_waitcnt vmcnt(12) lgkmcnt(0)" ::: "memory");
}
#define SB() __builtin_amdgcn_sched_barrier(0)

// ---------------- router: logits, softmax, argmax; NO global atomics ----------------
__global__ __launch_bounds__(256) void router_kernel(
    const float* __restrict__ x, const float* __restrict__ sw,
    const float* __restrict__ sb, float* __restrict__ pmax_out,
    int* __restrict__ routes, float* __restrict__ probs,
    unsigned short* __restrict__ xbf) {
  const int wave = threadIdx.x >> 6, lane = threadIdx.x & 63;
  const int t = blockIdx.x * 4 + wave;
  const float* xr = x + (size_t)t * D_DIM;
  float acc[8];
#pragma unroll
  for (int e = 0; e < 8; ++e) acc[e] = 0.f;
#pragma unroll
  for (int i = 0; i < 4; ++i) {
    const int d = i * 256 + lane * 4;
    float4 xv = *(const float4*)(xr + d);
    ushort4 h;
    h.x = f2bf(xv.x); h.y = f2bf(xv.y); h.z = f2bf(xv.z); h.w = f2bf(xv.w);
    *(ushort4*)(xbf + (size_t)t * D_DIM + d) = h;
    const float xs[4] = {xv.x, xv.y, xv.z, xv.w};
#pragma unroll
    for (int j = 0; j < 4; ++j) {
      const float4* swp = (const float4*)(sw + (size_t)(d + j) * 8);
      float4 w0 = swp[0], w1 = swp[1];
      acc[0] += xs[j] * w0.x; acc[1] += xs[j] * w0.y;
      acc[2] += xs[j] * w0.z; acc[3] += xs[j] * w0.w;
      acc[4] += xs[j] * w1.x; acc[5] += xs[j] * w1.y;
      acc[6] += xs[j] * w1.z; acc[7] += xs[j] * w1.w;
    }
  }
#pragma unroll
  for (int e = 0; e < 8; ++e) {
    float v = acc[e];
    for (int o = 32; o > 0; o >>= 1) v += __shfl_down(v, o, 64);
    acc[e] = v;
  }
  if (lane == 0) {
#pragma unroll
    for (int e = 0; e < 8; ++e) acc[e] += sb[e];
    int am = 0; float mx = acc[0];
#pragma unroll
    for (int e = 1; e < 8; ++e) if (acc[e] > mx) { mx = acc[e]; am = e; }  // first-max wins
    float p[8]; float s = 0.f;
#pragma unroll
    for (int e = 0; e < 8; ++e) { p[e] = expf(acc[e] - mx); s += p[e]; }
    float inv = 1.0f / s;
    pmax_out[t] = inv;
    routes[t] = am;
#pragma unroll
    for (int e = 0; e < 8; ++e) probs[(size_t)t * 8 + e] = p[e] * inv;
  }
}

// -------- plan: counts/psums reduce, offsets, perm init, scatter (fused) --------
__global__ __launch_bounds__(256) void plan_kernel(
    const int* __restrict__ routes, const float* __restrict__ probs,
    int* __restrict__ off, int* __restrict__ perm_out, int* __restrict__ perm_src,
    float* __restrict__ out_counts, float* __restrict__ out_psums,
    float* __restrict__ out_zero) {
  __shared__ int cnt[8];
  __shared__ int cur[8];
  __shared__ int offs[9];
  __shared__ float red[256][8];
  const int tid = threadIdx.x;
  if (tid < 8) cnt[tid] = 0;
  for (int i = tid; i < RPMAX; i += 256) { perm_out[i] = -1; perm_src[i] = 0; }
  __syncthreads();
  float loc[8];
#pragma unroll
  for (int e = 0; e < 8; ++e) loc[e] = 0.f;
  for (int t = tid; t < T_TOK; t += 256) {
    atomicAdd(&cnt[routes[t]], 1);
    const float4* p = (const float4*)(probs + (size_t)t * 8);
    float4 a = p[0], b = p[1];
    loc[0] += a.x; loc[1] += a.y; loc[2] += a.z; loc[3] += a.w;
    loc[4] += b.x; loc[5] += b.y; loc[6] += b.z; loc[7] += b.w;
  }
#pragma unroll
  for (int e = 0; e < 8; ++e) red[tid][e] = loc[e];
  __syncthreads();
  for (int s = 128; s >= 1; s >>= 1) {
    if (tid < s) {
#pragma unroll
      for (int e = 0; e < 8; ++e) red[tid][e] += red[tid + s][e];
    }
    __syncthreads();
  }
  if (tid == 0) {
    int o = 0;
    for (int e = 0; e < 8; ++e) { offs[e] = o; o += ((cnt[e] + 127) >> 7) << 7; }
    offs[8] = o;
    *out_zero = 0.0f;
  }
  __syncthreads();
  if (tid < 9) off[tid] = offs[tid];
  if (tid < 8) {
    cur[tid] = offs[tid];
    out_counts[tid] = (float)cnt[tid];
    out_psums[tid] = red[0][tid];
  }
  __syncthreads();
  // scatter: token -> gathered slot (LDS cursors; any within-expert order is valid)
  for (int t = tid; t < T_TOK; t += 256) {
    int e = routes[t];
    int pos = atomicAdd(&cur[e], 1);
    perm_out[pos] = t;
    perm_src[pos] = t;
  }
}

// ---------------- fused grouped GEMM, depth-3 B prefetch ----------------
// 128x64 tile, BK=64, 4 waves (2m x 2n), each wave 64x32 out. LDS 64KB.
// A bf16 via global_load_lds staged 2 K-steps ahead (3 rotating bufs, key row&7).
// B: fp32 W -> float4 loads staged THREE K-steps ahead (3 reg sets) -> cvt_pk bf16
// -> 4x4 reg transpose -> ds_write_b64, key ((nl>>2)+2*(nl&3))&7.
// Per iter FIFO: A(t+2)[4] then B(t+3)[4]; B_STORE implicit-waits B(t+1) (2 iters
// old); explicit vmcnt(12) drains A(t+1) only -> 12 loads in flight across barrier.
template <int K_, int N_, bool FIRST, bool NCHUNK>
__global__ __launch_bounds__(256, 2) void gemm_fused(
    const unsigned short* __restrict__ A,    // FIRST: xbf [T][K_]; else H [RP][K_]
    const float* __restrict__ W,             // [E][K_][N_] fp32
    const float* __restrict__ Bias,          // [E][N_]
    const int* __restrict__ off,
    const int* __restrict__ perm_src, const int* __restrict__ perm_out,
    const float* __restrict__ pmax,
    unsigned short* __restrict__ Hout, float* __restrict__ Out) {
  constexpr int NT = K_ / BK;                // 16 or 64 (even, >=4)
  __shared__ __align__(16) unsigned short As[3][128 * 64];
  __shared__ __align__(16) unsigned short Bs[2][64 * 64];
  const int tid = threadIdx.x;
  // XCD-chunked bijective swizzle (grid size multiple of 8)
  const int nbx = gridDim.x, nby = gridDim.y;
  const int lin = blockIdx.y * nbx + blockIdx.x;
  const int chunkg = (nbx * nby) >> 3;
  const int newlin = (lin & 7) * chunkg + (lin >> 3);
  const int bx = NCHUNK ? (newlin / nby) : (newlin % nbx);
  const int by = NCHUNK ? (newlin % nby) : (newlin / nbx);
  const int rowbase = by * 128;
  if (rowbase >= off[8]) return;
  int e = 0;
#pragma unroll
  for (int i = 1; i <= 7; ++i) if (rowbase >= off[i]) e = i;
  const int n0 = bx * 64;
  const int wave = tid >> 6, lane = tid & 63;
  const int wm = wave >> 1, wn = wave & 1;
  const float* Wn0 = W + (size_t)e * K_ * N_ + n0;

  // A: per-lane pre-swizzled global sources; LDS linear, src chunk XOR'd (key row&7)
  const unsigned short* aSrc[4];
#pragma unroll
  for (int c = 0; c < 4; ++c) {
    int ca = (wave * 4 + c) * 64 + lane;      // 16B-chunk id, 0..1023
    int row = ca >> 3, slot = ca & 7;
    int sc = slot ^ (row & 7);
    size_t arow = FIRST ? (size_t)perm_src[rowbase + row] : (size_t)(rowbase + row);
    aSrc[c] = A + arow * K_ + sc * 8;
  }

  const int nq = lane & 15;                  // n-quad 0..15
  const int qg = lane >> 4;                  // k-quad group 0..3
  fx4 brA[4], brB[4], brT[4];                // depth-3 B prefetch register sets

  auto A_STAGE = [&](int kt, unsigned short* Asb) {
#pragma unroll
    for (int c = 0; c < 4; ++c)
      load_lds16(aSrc[c] + kt, Asb + (wave * 4 + c) * 512);
  };
  auto B_LOAD = [&](int kt, fx4* br) {
#pragma unroll
    for (int j = 0; j < 4; ++j)
      br[j] = *(const fx4*)(Wn0 + (size_t)(kt + wave * 16 + qg * 4 + j) * N_ + nq * 4);
  };
  auto B_STORE = [&](fx4* br, unsigned short* Bsb) {
    const int c16 = wave * 2 + (qg >> 1);
    const int h4 = (qg & 1) * 4;             // 8B half (u16 units)
#pragma unroll
    for (int i = 0; i < 4; ++i) {
      const int nl = nq * 4 + i;
      const int key = ((nl >> 2) + 2 * (nl & 3)) & 7;
      uint32_t d0 = cvtpk_bf16(br[0][i], br[1][i]);
      uint32_t d1 = cvtpk_bf16(br[2][i], br[3][i]);
      *(uint2*)(Bsb + nl * 64 + (c16 ^ key) * 8 + h4) = make_uint2(d0, d1);
    }
  };

  fx4 acc[4][2];
#pragma unroll
  for (int a = 0; a < 4; ++a)
#pragma unroll
    for (int b = 0; b < 2; ++b) acc[a][b] = (fx4){0.f, 0.f, 0.f, 0.f};

  auto COMPUTE = [&](const unsigned short* Asb, const unsigned short* Bsb) {
    __builtin_amdgcn_s_setprio(1);
#pragma unroll
    for (int kk = 0; kk < 2; ++kk) {
      bfx8 af[4], bf[2];
#pragma unroll
      for (int fm = 0; fm < 4; ++fm) {
        int r = wm * 64 + fm * 16 + (lane & 15);
        int c = (kk * 4 + (lane >> 4)) ^ (r & 7);
        af[fm] = *(const bfx8*)(Asb + r * 64 + c * 8);
      }
#pragma unroll
      for (int fn = 0; fn < 2; ++fn) {
        int nn = wn * 32 + fn * 16 + (lane & 15);
        int key = ((nn >> 2) + 2 * (nn & 3)) & 7;
        int c = (kk * 4 + (lane >> 4)) ^ key;
        bf[fn] = *(const bfx8*)(Bsb + nn * 64 + c * 8);
      }
#pragma unroll
      for (int fm = 0; fm < 4; ++fm)
#pragma unroll
        for (int fn = 0; fn < 2; ++fn)
          acc[fm][fn] = __builtin_amdgcn_mfma_f32_16x16x32_bf16(
              af[fm], bf[fn], acc[fm][fn], 0, 0, 0);
    }
    __builtin_amdgcn_s_setprio(0);
  };

  unsigned short *a0 = As[0], *a1 = As[1], *a2 = As[2];

  // ---- prologue: FIFO A0,B0,A1,B1,B2; store B0; 12 loads left in flight ----
  A_STAGE(0, a0); SB();
  B_LOAD(0, brT); SB();
  A_STAGE(BK, a1); SB();
  B_LOAD(BK, brA); SB();
  B_LOAD(2 * BK, brB);
  B_STORE(brT, Bs[0]);                       // implicit reg-wait drains A0,B0
  vm_wait_lgkm<12>();                        // A1,B1,B2 stay in flight
  __builtin_amdgcn_s_barrier();

  // ---- main loop ----
#pragma unroll 2
  for (int t = 0; t < NT - 3; ++t) {
    A_STAGE((t + 2) * BK, a2); SB();         // A before B in FIFO
    B_LOAD((t + 3) * BK, brT);
    COMPUTE(a0, Bs[t & 1]);
    B_STORE(brA, Bs[(t + 1) & 1]);           // waits B(t+1) (2 iters old)
    vm_wait_lgkm<12>();                      // drain A(t+1); keep B(t+2),A(t+2),B(t+3)
    __builtin_amdgcn_s_barrier();
    { unsigned short* tmp = a0; a0 = a1; a1 = a2; a2 = tmp; }
#pragma unroll
    for (int j = 0; j < 4; ++j) { brA[j] = brB[j]; brB[j] = brT[j]; }
  }
  // t = NT-3 (computes Bs[1] since NT even)
  A_STAGE((NT - 1) * BK, a2);
  COMPUTE(a0, Bs[1]);
  B_STORE(brA, Bs[0]);                       // waits B(NT-2)
  vm_wait_lgkm<8>();                         // drain A(NT-2); keep B(NT-1),A(NT-1)
  __builtin_amdgcn_s_barrier();
  { unsigned short* tmp = a0; a0 = a1; a1 = a2; a2 = tmp; }
#pragma unroll
  for (int j = 0; j < 4; ++j) brA[j] = brB[j];
  // t = NT-2
  COMPUTE(a0, Bs[0]);
  B_STORE(brA, Bs[1]);                       // waits B(NT-1)
  vm_wait_lgkm<0>();                         // drain A(NT-1)
  __builtin_amdgcn_s_barrier();
  { unsigned short* tmp = a0; a0 = a1; a1 = tmp; }
  // t = NT-1
  COMPUTE(a0, Bs[1]);

  // ---- epilogue ----
  const int colbase = n0 + wn * 32;
  if (FIRST) {
#pragma unroll
    for (int fn = 0; fn < 2; ++fn) {
      int colg = colbase + fn * 16 + (lane & 15);
      float bv = Bias[(size_t)e * N_ + colg];
#pragma unroll
      for (int fm = 0; fm < 4; ++fm) {
        int rg = rowbase + wm * 64 + fm * 16 + ((lane >> 4) << 2);
#pragma unroll
        for (int j = 0; j < 4; ++j) {
          float v = fmaxf(acc[fm][fn][j] + bv, 0.f);
          Hout[(size_t)(rg + j) * N_ + colg] = f2bf(v);
        }
      }
    }
  } else {
#pragma unroll
    for (int fm = 0; fm < 4; ++fm) {
      int rg = rowbase + wm * 64 + fm * 16 + ((lane >> 4) << 2);
#pragma unroll
      for (int j = 0; j < 4; ++j) {
        int tok = perm_out[rg + j];
        if (tok < 0) continue;
        float pm = pmax[tok];
#pragma unroll
        for (int fn = 0; fn < 2; ++fn) {
          int colg = colbase + fn * 16 + (lane & 15);
          Out[(size_t)tok * N_ + colg] = (acc[fm][fn][j] + Bias[(size_t)e * N_ + colg]) * pm;
        }
      }
    }
  }
}

extern "C" void kernel_launch(void* const* d_in, const int* in_sizes, int n_in,
                              void* d_out, int out_size, void* d_ws, size_t ws_size,
                              hipStream_t stream) {
  const float* x  = (const float*)d_in[0];
  const float* sw = (const float*)d_in[1];
  const float* sb = (const float*)d_in[2];
  const float* w1 = (const float*)d_in[3];
  const float* b1 = (const float*)d_in[4];
  const float* w2 = (const float*)d_in[5];
  const float* b2 = (const float*)d_in[6];
  float* out = (float*)d_out;

  char* ws = (char*)d_ws;
  int*   off      = (int*)(ws + 0);          // 9 ints
  int*   routes   = (int*)(ws + 1024);       // 2048 ints
  int*   perm_out = (int*)(ws + 16384);      // RPMAX ints (pads -1)
  int*   perm_src = (int*)(ws + 32768);      // RPMAX ints (pads 0)
  float* probs    = (float*)(ws + 49152);    // 2048x8 fp32
  unsigned short* xbf = (unsigned short*)(ws + (1u << 20));   // 4 MB
  unsigned short* H   = (unsigned short*)(ws + (8u << 20));   // RPMAX x 4096 bf16 = 24 MB

  // d_out layout: final(2097152) | counts(8) | psums(8) | 0(1) | pmax(2048)
  float* out_final  = out;
  float* out_counts = out + 2097152;
  float* out_psums  = out + 2097160;
  float* out_zero   = out + 2097168;
  float* out_pmax   = out + 2097169;

  router_kernel<<<T_TOK / 4, 256, 0, stream>>>(x, sw, sb, out_pmax, routes, probs, xbf);
  plan_kernel<<<1, 256, 0, stream>>>(routes, probs, off, perm_out, perm_src,
                                     out_counts, out_psums, out_zero);

  // GEMM1: gather(xbf)[RP,1024] x W1 -> H (relu, bf16). n-chunked XCD swizzle.
  gemm_fused<D_DIM, F_DIM, true, true>
      <<<dim3(F_DIM / 64, RPMAX / 128), 256, 0, stream>>>(
          xbf, w1, b1, off, perm_src, perm_out, nullptr, H, nullptr);
  // GEMM2: H[RP,4096] x W2 -> out (bias, *pmax, scatter fp32). m-chunked swizzle.
  gemm_fused<F_DIM, D_DIM, false, false>
      <<<dim3(D_DIM / 64, RPMAX / 128), 256, 0, stream>>>(
          H, w2, b2, off, perm_src, perm_out, out_pmax, nullptr, out_final);
}

// Round 9
// 150.943 us; speedup vs baseline: 1.1080x; 1.1048x over previous
//
#include <hip/hip_runtime.h>
#include <stdint.h>

// Problem constants (B=2,S=1024,D=1024,F=4096,E=8)
#define T_TOK 2048
#define D_DIM 1024
#define F_DIM 4096
#define E_NUM 8
#define RPMAX 3072   // max padded rows: sum of per-expert ceil(cnt,128)
#define BK 64

typedef __attribute__((ext_vector_type(8))) short bfx8;   // 8 bf16 (4 VGPR)
typedef __attribute__((ext_vector_type(4))) float fx4;    // MFMA accum / staging

__device__ __forceinline__ unsigned short f2bf(float f) {
  union { float f; uint32_t u; } v; v.f = f;
  uint32_t u = v.u;
  u += 0x7FFFu + ((u >> 16) & 1u);   // round-to-nearest-even
  return (unsigned short)(u >> 16);
}

__device__ __forceinline__ void load_lds16(const unsigned short* g, unsigned short* l) {
  __builtin_amdgcn_global_load_lds(
      (const __attribute__((address_space(1))) void*)g,
      (__attribute__((address_space(3))) void*)l, 16, 0, 0);
}

__device__ __forceinline__ uint32_t cvtpk_bf16(float lo, float hi) {
  uint32_t d;
  asm("v_cvt_pk_bf16_f32 %0, %1, %2" : "=v"(d) : "v"(lo), "v"(hi));
  return d;
}

template <int N>
__device__ __forceinline__ void vm_wait_lgkm() {
  if constexpr (N == 0) asm volatile("s_waitcnt vmcnt(0) lgkmcnt(0)" ::: "memory");
  else if constexpr (N == 8) asm volatile("s_waitcnt vmcnt(8) lgkmcnt(0)" ::: "memory");
  else if constexpr (N == 12) asm volatile("s_waitcnt vmcnt(12) lgkmcnt(0)" ::: "memory");
}
#define SB() __builtin_amdgcn_sched_barrier(0)

// ---------------- router: logits, softmax, argmax; NO global atomics ----------------
__global__ __launch_bounds__(256) void router_kernel(
    const float* __restrict__ x, const float* __restrict__ sw,
    const float* __restrict__ sb, float* __restrict__ pmax_out,
    int* __restrict__ routes, float* __restrict__ probs,
    unsigned short* __restrict__ xbf) {
  const int wave = threadIdx.x >> 6, lane = threadIdx.x & 63;
  const int t = blockIdx.x * 4 + wave;
  const float* xr = x + (size_t)t * D_DIM;
  float acc[8];
#pragma unroll
  for (int e = 0; e < 8; ++e) acc[e] = 0.f;
#pragma unroll
  for (int i = 0; i < 4; ++i) {
    const int d = i * 256 + lane * 4;
    float4 xv = *(const float4*)(xr + d);
    ushort4 h;
    h.x = f2bf(xv.x); h.y = f2bf(xv.y); h.z = f2bf(xv.z); h.w = f2bf(xv.w);
    *(ushort4*)(xbf + (size_t)t * D_DIM + d) = h;
    const float xs[4] = {xv.x, xv.y, xv.z, xv.w};
#pragma unroll
    for (int j = 0; j < 4; ++j) {
      const float4* swp = (const float4*)(sw + (size_t)(d + j) * 8);
      float4 w0 = swp[0], w1 = swp[1];
      acc[0] += xs[j] * w0.x; acc[1] += xs[j] * w0.y;
      acc[2] += xs[j] * w0.z; acc[3] += xs[j] * w0.w;
      acc[4] += xs[j] * w1.x; acc[5] += xs[j] * w1.y;
      acc[6] += xs[j] * w1.z; acc[7] += xs[j] * w1.w;
    }
  }
#pragma unroll
  for (int e = 0; e < 8; ++e) {
    float v = acc[e];
    for (int o = 32; o > 0; o >>= 1) v += __shfl_down(v, o, 64);
    acc[e] = v;
  }
  if (lane == 0) {
#pragma unroll
    for (int e = 0; e < 8; ++e) acc[e] += sb[e];
    int am = 0; float mx = acc[0];
#pragma unroll
    for (int e = 1; e < 8; ++e) if (acc[e] > mx) { mx = acc[e]; am = e; }  // first-max wins
    float p[8]; float s = 0.f;
#pragma unroll
    for (int e = 0; e < 8; ++e) { p[e] = expf(acc[e] - mx); s += p[e]; }
    float inv = 1.0f / s;
    pmax_out[t] = inv;
    routes[t] = am;
#pragma unroll
    for (int e = 0; e < 8; ++e) probs[(size_t)t * 8 + e] = p[e] * inv;
  }
}

// -------- plan: counts/psums reduce, offsets, perm init, scatter (fused) --------
__global__ __launch_bounds__(256) void plan_kernel(
    const int* __restrict__ routes, const float* __restrict__ probs,
    int* __restrict__ off, int* __restrict__ perm_out, int* __restrict__ perm_src,
    float* __restrict__ out_counts, float* __restrict__ out_psums,
    float* __restrict__ out_zero) {
  __shared__ int cnt[8];
  __shared__ int cur[8];
  __shared__ int offs[9];
  __shared__ float red[256][8];
  const int tid = threadIdx.x;
  if (tid < 8) cnt[tid] = 0;
  for (int i = tid; i < RPMAX; i += 256) { perm_out[i] = -1; perm_src[i] = 0; }
  __syncthreads();
  float loc[8];
#pragma unroll
  for (int e = 0; e < 8; ++e) loc[e] = 0.f;
  for (int t = tid; t < T_TOK; t += 256) {
    atomicAdd(&cnt[routes[t]], 1);
    const float4* p = (const float4*)(probs + (size_t)t * 8);
    float4 a = p[0], b = p[1];
    loc[0] += a.x; loc[1] += a.y; loc[2] += a.z; loc[3] += a.w;
    loc[4] += b.x; loc[5] += b.y; loc[6] += b.z; loc[7] += b.w;
  }
#pragma unroll
  for (int e = 0; e < 8; ++e) red[tid][e] = loc[e];
  __syncthreads();
  for (int s = 128; s >= 1; s >>= 1) {
    if (tid < s) {
#pragma unroll
      for (int e = 0; e < 8; ++e) red[tid][e] += red[tid + s][e];
    }
    __syncthreads();
  }
  if (tid == 0) {
    int o = 0;
    for (int e = 0; e < 8; ++e) { offs[e] = o; o += ((cnt[e] + 127) >> 7) << 7; }
    offs[8] = o;
    *out_zero = 0.0f;
  }
  __syncthreads();
  if (tid < 9) off[tid] = offs[tid];
  if (tid < 8) {
    cur[tid] = offs[tid];
    out_counts[tid] = (float)cnt[tid];
    out_psums[tid] = red[0][tid];
  }
  __syncthreads();
  // scatter: token -> gathered slot (LDS cursors; any within-expert order is valid)
  for (int t = tid; t < T_TOK; t += 256) {
    int e = routes[t];
    int pos = atomicAdd(&cur[e], 1);
    perm_out[pos] = t;
    perm_src[pos] = t;
  }
}

// ---------------- fused grouped GEMM, depth-3 B prefetch (4 static sets) ----------
// 128x64 tile, BK=64, 4 waves (2m x 2n), each wave 64x32 out. LDS 64KB.
// A bf16 via global_load_lds staged 2 steps ahead (3 rotating bufs, key row&7).
// B: fp32 W staged THREE steps ahead into 4 NAMED reg sets (no copies!) ->
// cvt_pk bf16 -> 4x4 reg transpose -> ds_write_b64, key ((nl>>2)+2*(nl&3))&7.
// Iter u: A(u+2), B(u+3)->s[(u+3)&3] | COMPUTE | STORE s[(u+1)&3] (B(u+1), 2 iters
// old; implicit vmcnt(16)) | vmcnt(12): drain A(u+1), keep B(u+2),A(u+2),B(u+3).
template <int K_, int N_, bool FIRST, bool NCHUNK>
__global__ __launch_bounds__(256, 2) void gemm_fused(
    const unsigned short* __restrict__ A,    // FIRST: xbf [T][K_]; else H [RP][K_]
    const float* __restrict__ W,             // [E][K_][N_] fp32
    const float* __restrict__ Bias,          // [E][N_]
    const int* __restrict__ off,
    const int* __restrict__ perm_src, const int* __restrict__ perm_out,
    const float* __restrict__ pmax,
    unsigned short* __restrict__ Hout, float* __restrict__ Out) {
  constexpr int NT = K_ / BK;                // 16 or 64; (NT-4)%4==0
  __shared__ __align__(16) unsigned short As[3][128 * 64];
  __shared__ __align__(16) unsigned short Bs[2][64 * 64];
  const int tid = threadIdx.x;
  // XCD-chunked bijective swizzle (grid size multiple of 8)
  const int nbx = gridDim.x, nby = gridDim.y;
  const int lin = blockIdx.y * nbx + blockIdx.x;
  const int chunkg = (nbx * nby) >> 3;
  const int newlin = (lin & 7) * chunkg + (lin >> 3);
  const int bx = NCHUNK ? (newlin / nby) : (newlin % nbx);
  const int by = NCHUNK ? (newlin % nby) : (newlin / nbx);
  const int rowbase = by * 128;
  if (rowbase >= off[8]) return;
  int e = 0;
#pragma unroll
  for (int i = 1; i <= 7; ++i) if (rowbase >= off[i]) e = i;
  const int n0 = bx * 64;
  const int wave = tid >> 6, lane = tid & 63;
  const int wm = wave >> 1, wn = wave & 1;
  const float* Wn0 = W + (size_t)e * K_ * N_ + n0;

  // A: per-lane pre-swizzled global sources; LDS linear, src chunk XOR'd (key row&7)
  const unsigned short* aSrc[4];
#pragma unroll
  for (int c = 0; c < 4; ++c) {
    int ca = (wave * 4 + c) * 64 + lane;      // 16B-chunk id, 0..1023
    int row = ca >> 3, slot = ca & 7;
    int sc = slot ^ (row & 7);
    size_t arow = FIRST ? (size_t)perm_src[rowbase + row] : (size_t)(rowbase + row);
    aSrc[c] = A + arow * K_ + sc * 8;
  }

  const int nq = lane & 15;                  // n-quad 0..15
  const int qg = lane >> 4;                  // k-quad group 0..3
  fx4 s0[4], s1[4], s2[4], s3[4];            // 4 named B prefetch sets (depth 3)

  auto A_STAGE = [&](int kt, unsigned short* Asb) {
#pragma unroll
    for (int c = 0; c < 4; ++c)
      load_lds16(aSrc[c] + kt, Asb + (wave * 4 + c) * 512);
  };
  auto B_LOAD = [&](int kt, fx4* br) {
#pragma unroll
    for (int j = 0; j < 4; ++j)
      br[j] = *(const fx4*)(Wn0 + (size_t)(kt + wave * 16 + qg * 4 + j) * N_ + nq * 4);
  };
  auto B_STORE = [&](fx4* br, unsigned short* Bsb) {
    const int c16 = wave * 2 + (qg >> 1);
    const int h4 = (qg & 1) * 4;             // 8B half (u16 units)
#pragma unroll
    for (int i = 0; i < 4; ++i) {
      const int nl = nq * 4 + i;
      const int key = ((nl >> 2) + 2 * (nl & 3)) & 7;
      uint32_t d0 = cvtpk_bf16(br[0][i], br[1][i]);
      uint32_t d1 = cvtpk_bf16(br[2][i], br[3][i]);
      *(uint2*)(Bsb + nl * 64 + (c16 ^ key) * 8 + h4) = make_uint2(d0, d1);
    }
  };

  fx4 acc[4][2];
#pragma unroll
  for (int a = 0; a < 4; ++a)
#pragma unroll
    for (int b = 0; b < 2; ++b) acc[a][b] = (fx4){0.f, 0.f, 0.f, 0.f};

  auto COMPUTE = [&](const unsigned short* Asb, const unsigned short* Bsb) {
    __builtin_amdgcn_s_setprio(1);
#pragma unroll
    for (int kk = 0; kk < 2; ++kk) {
      bfx8 af[4], bf[2];
#pragma unroll
      for (int fm = 0; fm < 4; ++fm) {
        int r = wm * 64 + fm * 16 + (lane & 15);
        int c = (kk * 4 + (lane >> 4)) ^ (r & 7);
        af[fm] = *(const bfx8*)(Asb + r * 64 + c * 8);
      }
#pragma unroll
      for (int fn = 0; fn < 2; ++fn) {
        int nn = wn * 32 + fn * 16 + (lane & 15);
        int key = ((nn >> 2) + 2 * (nn & 3)) & 7;
        int c = (kk * 4 + (lane >> 4)) ^ key;
        bf[fn] = *(const bfx8*)(Bsb + nn * 64 + c * 8);
      }
#pragma unroll
      for (int fm = 0; fm < 4; ++fm)
#pragma unroll
        for (int fn = 0; fn < 2; ++fn)
          acc[fm][fn] = __builtin_amdgcn_mfma_f32_16x16x32_bf16(
              af[fm], bf[fn], acc[fm][fn], 0, 0, 0);
    }
    __builtin_amdgcn_s_setprio(0);
  };

  unsigned short *a0 = As[0], *a1 = As[1], *a2 = As[2];
#define ROT_A { unsigned short* tmp_ = a0; a0 = a1; a1 = a2; a2 = tmp_; }

  // one pipeline iteration; LD = set receiving B(u+3), ST = set holding B(u+1)
#define ITER(u, LD, ST, W_N)                                   \
  {                                                            \
    A_STAGE(((u) + 2) * BK, a2); SB();                         \
    B_LOAD(((u) + 3) * BK, LD); SB();                          \
    COMPUTE(a0, Bs[(u) & 1]);                                  \
    B_STORE(ST, Bs[((u) + 1) & 1]);                            \
    vm_wait_lgkm<W_N>();                                       \
    __builtin_amdgcn_s_barrier();                              \
    ROT_A;                                                     \
  }

  // ---- prologue: FIFO A0,B0(s0),A1,B1(s1),B2(s2); store B0; barrier ----
  A_STAGE(0, a0); SB();
  B_LOAD(0, s0); SB();
  A_STAGE(BK, a1); SB();
  B_LOAD(BK, s1); SB();
  B_LOAD(2 * BK, s2);
  B_STORE(s0, Bs[0]);                        // implicit wait drains A0,B0
  vm_wait_lgkm<12>();                        // A1,B1,B2 stay in flight
  __builtin_amdgcn_s_barrier();

  // ---- main loop: 4x unrolled, static set roles, no copies ----
  for (int t = 0; t < NT - 4; t += 4) {
    ITER(t + 0, s3, s1, 12);
    ITER(t + 1, s0, s2, 12);
    ITER(t + 2, s1, s3, 12);
    ITER(t + 3, s2, s0, 12);
  }
  // ---- peeled tail: u = NT-4 .. NT-1 (NT-4 ≡ 0 mod 4) ----
  // u = NT-4: last B issue (B(NT-1)->s3), A(NT-2)
  ITER(NT - 4, s3, s1, 12);
  // u = NT-3: last A issue (A(NT-1)); no B issue
  A_STAGE((NT - 1) * BK, a2);
  COMPUTE(a0, Bs[(NT - 3) & 1]);
  B_STORE(s2, Bs[(NT - 2) & 1]);             // B(NT-2); implicit drain
  vm_wait_lgkm<8>();                         // drain A(NT-2); keep B(NT-1),A(NT-1)
  __builtin_amdgcn_s_barrier();
  ROT_A;
  // u = NT-2
  COMPUTE(a0, Bs[(NT - 2) & 1]);
  B_STORE(s3, Bs[(NT - 1) & 1]);             // B(NT-1)
  vm_wait_lgkm<0>();                         // drain A(NT-1)
  __builtin_amdgcn_s_barrier();
  ROT_A;
  // u = NT-1
  COMPUTE(a0, Bs[(NT - 1) & 1]);
#undef ITER
#undef ROT_A

  // ---- epilogue ----
  const int colbase = n0 + wn * 32;
  if (FIRST) {
#pragma unroll
    for (int fn = 0; fn < 2; ++fn) {
      int colg = colbase + fn * 16 + (lane & 15);
      float bv = Bias[(size_t)e * N_ + colg];
#pragma unroll
      for (int fm = 0; fm < 4; ++fm) {
        int rg = rowbase + wm * 64 + fm * 16 + ((lane >> 4) << 2);
#pragma unroll
        for (int j = 0; j < 4; ++j) {
          float v = fmaxf(acc[fm][fn][j] + bv, 0.f);
          Hout[(size_t)(rg + j) * N_ + colg] = f2bf(v);
        }
      }
    }
  } else {
#pragma unroll
    for (int fm = 0; fm < 4; ++fm) {
      int rg = rowbase + wm * 64 + fm * 16 + ((lane >> 4) << 2);
#pragma unroll
      for (int j = 0; j < 4; ++j) {
        int tok = perm_out[rg + j];
        if (tok < 0) continue;
        float pm = pmax[tok];
#pragma unroll
        for (int fn = 0; fn < 2; ++fn) {
          int colg = colbase + fn * 16 + (lane & 15);
          Out[(size_t)tok * N_ + colg] = (acc[fm][fn][j] + Bias[(size_t)e * N_ + colg]) * pm;
        }
      }
    }
  }
}

extern "C" void kernel_launch(void* const* d_in, const int* in_sizes, int n_in,
                              void* d_out, int out_size, void* d_ws, size_t ws_size,
                              hipStream_t stream) {
  const float* x  = (const float*)d_in[0];
  const float* sw = (const float*)d_in[1];
  const float* sb = (const float*)d_in[2];
  const float* w1 = (const float*)d_in[3];
  const float* b1 = (const float*)d_in[4];
  const float* w2 = (const float*)d_in[5];
  const float* b2 = (const float*)d_in[6];
  float* out = (float*)d_out;

  char* ws = (char*)d_ws;
  int*   off      = (int*)(ws + 0);          // 9 ints
  int*   routes   = (int*)(ws + 1024);       // 2048 ints
  int*   perm_out = (int*)(ws + 16384);      // RPMAX ints (pads -1)
  int*   perm_src = (int*)(ws + 32768);      // RPMAX ints (pads 0)
  float* probs    = (float*)(ws + 49152);    // 2048x8 fp32
  unsigned short* xbf = (unsigned short*)(ws + (1u << 20));   // 4 MB
  unsigned short* H   = (unsigned short*)(ws + (8u << 20));   // RPMAX x 4096 bf16 = 24 MB

  // d_out layout: final(2097152) | counts(8) | psums(8) | 0(1) | pmax(2048)
  float* out_final  = out;
  float* out_counts = out + 2097152;
  float* out_psums  = out + 2097160;
  float* out_zero   = out + 2097168;
  float* out_pmax   = out + 2097169;

  router_kernel<<<T_TOK / 4, 256, 0, stream>>>(x, sw, sb, out_pmax, routes, probs, xbf);
  plan_kernel<<<1, 256, 0, stream>>>(routes, probs, off, perm_out, perm_src,
                                     out_counts, out_psums, out_zero);

  // GEMM1: gather(xbf)[RP,1024] x W1 -> H (relu, bf16). n-chunked XCD swizzle.
  gemm_fused<D_DIM, F_DIM, true, true>
      <<<dim3(F_DIM / 64, RPMAX / 128), 256, 0, stream>>>(
          xbf, w1, b1, off, perm_src, perm_out, nullptr, H, nullptr);
  // GEMM2: H[RP,4096] x W2 -> out (bias, *pmax, scatter fp32). m-chunked swizzle.
  gemm_fused<F_DIM, D_DIM, false, false>
      <<<dim3(D_DIM / 64, RPMAX / 128), 256, 0, stream>>>(
          H, w2, b2, off, perm_src, perm_out, out_pmax, nullptr, out_final);
}